// Round 7
// baseline (840.276 us; speedup 1.0000x reference)
//
#include <hip/hip_runtime.h>
#include <hip/hip_bf16.h>
#include <cstdint>
#include <cstddef>

// ---------------------------------------------------------------------------
// EnhancedMultiHeadAttention on MI355X (gfx950).
// EXTERNAL dtype: fp32 (per reference). INTERNAL: bf16 MFMA, fp32 stats.
// Pipeline:
//   mix_kernel   : softmax(head_mixing fp32) -> MIXW fp32[16][16]
//   gemm<f32in>  : Q/K/V projections (A fp32->bf16, W fp32 transposed in LDS),
//                  Q pre-scaled 1/8.
//   transpose_v  : Vp[b,s,g*64+d] -> Vt[b,g,d,s]   (bf16)
//   pass1        : Z[b,h,q] = m + log l  (flash stats, MFMA QK^T), 1024 blocks.
//   pass2        : p=exp(s-Z), head-mix (VALU), PV (MFMA) -> f32 PARTIALS
//     Cross-block split-K (R8): grid 512 = (b, qt128, khalf), 256 thr/4 waves,
//     f32 partials summed in the Wo-GEMM A-staging.
//     R9 register diet: R6 measured VGPR 196 (arch) + 64 AGPR (cacc[4][4],
//     unified file on gfx950) = 260 > 256 -> 1 wave/SIMD (Occupancy 11.9%,
//     same as R0 despite 2x grid). Every phase latency-exposed, no overlap.
//     Changes: (a) mix j-split ma[4][8]->2x mah[4][4] (-16 VGPR, same FLOPs,
//     b64 P reads), (b) amdgpu_waves_per_eu(2) enforces total <=256,
//     (c) PSTR 40->36 (store banks qd->{0,8,16,24}, ln 2-way free) to halve
//     the 4.2M LDS bank-conflict cycles. Target: 2 waves/SIMD, Occ ~24%.
//   gemm<f32out> : (PP0+PP1) @ Wo + bo -> d_out fp32
// MFMA 16x16x32 bf16 layouts (m89/m91/m120-verified):
//   A: m=lane&15, k=(lane>>4)*8+j ; B: n=lane&15, k=(lane>>4)*8+j
//   C/D: col=lane&15, row=(lane>>4)*4+reg
// ---------------------------------------------------------------------------

typedef __bf16 bf16_t;
typedef __bf16 bf16x8 __attribute__((ext_vector_type(8)));
typedef __bf16 bf16x4 __attribute__((ext_vector_type(4)));
typedef float f32x4 __attribute__((ext_vector_type(4)));

#define B_ 2
#define S_ 2048
#define E_ 1024
#define H_ 16
#define D_ 64
#define PSTR 36  // padded k-stride of P tile in bf16 (72 B rows)

static __device__ __forceinline__ f32x4 mfma16(bf16x8 a, bf16x8 b, f32x4 c) {
  return __builtin_amdgcn_mfma_f32_16x16x32_bf16(a, b, c, 0, 0, 0);
}

// ---------------- mix = softmax(head_mixing, axis=-1), fp32 ----------------
__global__ void mix_kernel(const float* __restrict__ hm, float* __restrict__ mixw) {
  int g = threadIdx.x;
  if (g < H_) {
    float v[H_]; float mx = -1e30f;
    for (int h = 0; h < H_; h++) { v[h] = hm[g * H_ + h]; mx = fmaxf(mx, v[h]); }
    float s = 0.f;
    for (int h = 0; h < H_; h++) { v[h] = __expf(v[h] - mx); s += v[h]; }
    float inv = 1.f / s;
    for (int h = 0; h < H_; h++) mixw[g * H_ + h] = v[h] * inv;
  }
}

// ---------------- V transpose: Vp[b,s,g*64+d] -> Vt[(b*16+g)*64+d][s] ------
__global__ void transpose_v_kernel(const bf16_t* __restrict__ Vp, bf16_t* __restrict__ Vt) {
  __shared__ bf16_t t[32][33];
  const int tx = threadIdx.x & 31, ty = threadIdx.x >> 5;
  const int z = blockIdx.z, b = z >> 4, g = z & 15;
  const int s0 = blockIdx.x * 32, d0 = blockIdx.y * 32;
  const bf16_t* src = Vp + (size_t)b * S_ * E_ + g * 64;
  bf16_t* dst = Vt + (size_t)z * 64 * S_;
#pragma unroll
  for (int i = 0; i < 4; i++)
    t[ty + i * 8][tx] = src[(size_t)(s0 + ty + i * 8) * E_ + d0 + tx];
  __syncthreads();
#pragma unroll
  for (int i = 0; i < 4; i++)
    dst[(size_t)(d0 + ty + i * 8) * S_ + s0 + tx] = t[tx][ty + i * 8];
}

// ---------------- GEMM: C[4096,1024] = (A @ W + bias) * scale --------------
// AF32: A fp32 (else bf16). ASUM: A = A + A2 elementwise (both fp32).
// OF32: C fp32 (else bf16).
struct GemmSec {
  const void* A; const void* A2; const float* bias; const float* W; void* C; float scale;
};

template <bool AF32, bool OF32, bool ASUM>
__global__ __launch_bounds__(256) void gemm_kernel(GemmSec s0, GemmSec s1, GemmSec s2) {
  const int z = blockIdx.z;
  GemmSec p = (z == 0) ? s0 : ((z == 1) ? s1 : s2);
  const int tid = threadIdx.x;
  const int wave = tid >> 6, lane = tid & 63;
  const int ln = lane & 15, qd = lane >> 4;
  const int wm = wave >> 1, wn = wave & 1;
  const int row0 = blockIdx.y * 128, col0 = blockIdx.x * 128;

  __shared__ __align__(16) bf16_t As[128 * 32];  // [row 128][k 32]
  __shared__ __align__(16) bf16_t Bs[128 * 32];  // [n 128][k 32]

  f32x4 z4 = {0.f, 0.f, 0.f, 0.f};
  f32x4 acc[4][4];
#pragma unroll
  for (int i = 0; i < 4; i++)
#pragma unroll
    for (int j = 0; j < 4; j++) acc[i][j] = z4;

  for (int ks = 0; ks < E_ / 32; ks++) {
    const int kk = ks * 32;
#pragma unroll
    for (int cc = 0; cc < 2; cc++) {
      const int c = tid + cc * 256;
      const int r = c >> 2, kc = (c & 3) * 8;
      if (AF32) {
        const float* Af = (const float*)p.A;
        f32x4 f0 = *(const f32x4*)&Af[(size_t)(row0 + r) * E_ + kk + kc];
        f32x4 f1 = *(const f32x4*)&Af[(size_t)(row0 + r) * E_ + kk + kc + 4];
        if (ASUM) {
          const float* Ag = (const float*)p.A2;
          f0 += *(const f32x4*)&Ag[(size_t)(row0 + r) * E_ + kk + kc];
          f1 += *(const f32x4*)&Ag[(size_t)(row0 + r) * E_ + kk + kc + 4];
        }
        bf16x8 v;
#pragma unroll
        for (int j = 0; j < 4; j++) { v[j] = (bf16_t)f0[j]; v[4 + j] = (bf16_t)f1[j]; }
        *(bf16x8*)&As[r * 32 + kc] = v;
      } else {
        const bf16_t* Ab = (const bf16_t*)p.A;
        *(uint4*)&As[r * 32 + kc] = *(const uint4*)&Ab[(size_t)(row0 + r) * E_ + kk + kc];
      }
    }
#pragma unroll
    for (int cc = 0; cc < 2; cc++) {
      const int c = tid + cc * 256;
      const int kr = c & 31, nc = (c >> 5) * 8;
      f32x4 g0 = *(const f32x4*)&p.W[(size_t)(kk + kr) * E_ + col0 + nc];
      f32x4 g1 = *(const f32x4*)&p.W[(size_t)(kk + kr) * E_ + col0 + nc + 4];
#pragma unroll
      for (int j = 0; j < 4; j++) {
        Bs[(nc + j) * 32 + kr]     = (bf16_t)g0[j];
        Bs[(nc + 4 + j) * 32 + kr] = (bf16_t)g1[j];
      }
    }
    __syncthreads();
    bf16x8 af[4], bfr[4];
#pragma unroll
    for (int mt = 0; mt < 4; mt++) af[mt] = *(const bf16x8*)&As[(wm * 64 + mt * 16 + ln) * 32 + qd * 8];
#pragma unroll
    for (int nt = 0; nt < 4; nt++) bfr[nt] = *(const bf16x8*)&Bs[(wn * 64 + nt * 16 + ln) * 32 + qd * 8];
#pragma unroll
    for (int mt = 0; mt < 4; mt++)
#pragma unroll
      for (int nt = 0; nt < 4; nt++)
        acc[mt][nt] = mfma16(af[mt], bfr[nt], acc[mt][nt]);
    __syncthreads();
  }
#pragma unroll
  for (int nt = 0; nt < 4; nt++) {
    int col = col0 + wn * 64 + nt * 16 + ln;
    float bias_v = p.bias[col];
#pragma unroll
    for (int mt = 0; mt < 4; mt++) {
      int row = row0 + wm * 64 + mt * 16 + qd * 4;
#pragma unroll
      for (int r = 0; r < 4; r++) {
        float v = (acc[mt][nt][r] + bias_v) * p.scale;
        if (OF32) ((float*)p.C)[(size_t)(row + r) * E_ + col] = v;
        else      ((bf16_t*)p.C)[(size_t)(row + r) * E_ + col] = (bf16_t)v;
      }
    }
  }
}

// ---------------- pass 1: softmax stats Z = m + log(l) ---------------------
// grid (32,32), each wave handles 16 q rows -> 1024 blocks = 4 blocks/CU.
__global__ __launch_bounds__(256, 4) void pass1_kernel(const bf16_t* __restrict__ Qp,
                                                       const bf16_t* __restrict__ Kp,
                                                       float* __restrict__ Z) {
  const int qc = blockIdx.x;            // 0..31
  const int bh = blockIdx.y;
  const int b = bh >> 4, h = bh & 15;
  const int tid = threadIdx.x;
  const int wave = tid >> 6, lane = tid & 63;
  const int ln = lane & 15, qd = lane >> 4;
  const size_t rowbase = (size_t)b * S_;
  const int qbase = qc * 64 + wave * 16;

  bf16x8 qf[2];
#pragma unroll
  for (int db = 0; db < 2; db++)
    qf[db] = *(const bf16x8*)&Qp[(rowbase + qbase + ln) * E_ + h * 64 + db * 32 + qd * 8];

  float m[4], l[4];
#pragma unroll
  for (int r = 0; r < 4; r++) { m[r] = -1e30f; l[r] = 0.f; }

  for (int kt = 0; kt < S_ / 64; kt++) {
    bf16x8 kf[4][2];
#pragma unroll
    for (int nt = 0; nt < 4; nt++)
#pragma unroll
      for (int db = 0; db < 2; db++)
        kf[nt][db] = *(const bf16x8*)&Kp[(rowbase + kt * 64 + nt * 16 + ln) * E_ + h * 64 + db * 32 + qd * 8];
    f32x4 sc[4];
#pragma unroll
    for (int nt = 0; nt < 4; nt++) {
      f32x4 c0 = {0.f, 0.f, 0.f, 0.f};
      c0 = mfma16(qf[0], kf[nt][0], c0);
      sc[nt] = mfma16(qf[1], kf[nt][1], c0);
    }
#pragma unroll
    for (int r = 0; r < 4; r++) {
      float tmax = fmaxf(fmaxf(sc[0][r], sc[1][r]), fmaxf(sc[2][r], sc[3][r]));
      float mn = fmaxf(m[r], tmax);
      float add = __expf(sc[0][r] - mn) + __expf(sc[1][r] - mn) +
                  __expf(sc[2][r] - mn) + __expf(sc[3][r] - mn);
      l[r] = l[r] * __expf(m[r] - mn) + add;
      m[r] = mn;
    }
  }
#pragma unroll
  for (int r = 0; r < 4; r++) {
    float mm = m[r], ll = l[r];
    for (int mask = 1; mask < 16; mask <<= 1) {
      float mo = __shfl_xor(mm, mask);
      float lo = __shfl_xor(ll, mask);
      float mn = fmaxf(mm, mo);
      ll = ll * __expf(mm - mn) + lo * __expf(mo - mn);
      mm = mn;
    }
    if (ln == 0) {
      int q = qbase + qd * 4 + r;
      Z[(size_t)bh * S_ + q] = mm + __logf(ll);
    }
  }
}

// ---------------- pass 2: p=exp(s-Z), head-mix, PV -> f32 partials ---------
// Cross-block split-K. grid 512 = (b<<8)|(qt<<1)|kg, 256 thr / 4 waves.
// Wave wi: QK^T+exp for heads {4wi..4wi+3} over this block's k-half into
// Plds; head-mix (all 16 h, j-split into two bf16x4 halves to save 16 VGPR)
// + PV for groups {4wi..4wi+3}. Output f32 partials pp[kg]; kg halves summed
// in the Wo-GEMM A-staging. waves_per_eu(2): enforce arch+acc <= 256 regs
// (R6: 196+64=260 -> 1 wave/SIMD, occupancy stuck at 12%).
__global__ __launch_bounds__(256)
__attribute__((amdgpu_waves_per_eu(2)))
void pass2_kernel(const bf16_t* __restrict__ Qp,
                  const bf16_t* __restrict__ Kp,
                  const bf16_t* __restrict__ Vt,
                  const float* __restrict__ Z,
                  const float* __restrict__ mixw,
                  float* __restrict__ pp) {
  const int id = blockIdx.x;            // 0..511
  const int kg = id & 1;                // k-half
  const int qt = (id >> 1) & 127;
  const int b  = id >> 8;
  const int q0 = qt * 16;

  const int tid = threadIdx.x;
  const int wave = tid >> 6, lane = tid & 63;
  const int ln = lane & 15, qd = lane >> 4;
  const int h0 = wave * 4;              // 4 source heads == 4 output groups

  __shared__ __align__(16) bf16_t Plds[16 * 16 * PSTR];  // [h][q16][k PSTR]
  __shared__ float mixLds[256];
  mixLds[tid] = mixw[tid];

  const size_t rowbase = (size_t)b * S_;
  const int kbase = kg * (S_ / 2);      // contiguous k-half

  bf16x8 qf[4][2];
#pragma unroll
  for (int hh = 0; hh < 4; hh++)
#pragma unroll
    for (int db = 0; db < 2; db++)
      qf[hh][db] = *(const bf16x8*)&Qp[(rowbase + q0 + ln) * E_ + (h0 + hh) * 64 + db * 32 + qd * 8];

  float Zr[4][4];
#pragma unroll
  for (int hh = 0; hh < 4; hh++)
#pragma unroll
    for (int r = 0; r < 4; r++)
      Zr[hh][r] = Z[((size_t)(b * H_ + h0 + hh)) * S_ + q0 + qd * 4 + r];

  f32x4 z4 = {0.f, 0.f, 0.f, 0.f};
  f32x4 cacc[4][4];
#pragma unroll
  for (int g = 0; g < 4; g++)
#pragma unroll
    for (int nt = 0; nt < 4; nt++) cacc[g][nt] = z4;

  for (int t = 0; t < S_ / 64; t++) {   // 32 iters over this k-half
    const int kb = kbase + t * 32;
#pragma unroll
    for (int hh = 0; hh < 4; hh++) {
      bf16x8 kf[2][2];
#pragma unroll
      for (int n2 = 0; n2 < 2; n2++)
#pragma unroll
        for (int db = 0; db < 2; db++)
          kf[n2][db] = *(const bf16x8*)&Kp[(rowbase + kb + n2 * 16 + ln) * E_ + (h0 + hh) * 64 + db * 32 + qd * 8];
#pragma unroll
      for (int n2 = 0; n2 < 2; n2++) {
        f32x4 c0;
        c0[0] = -Zr[hh][0]; c0[1] = -Zr[hh][1]; c0[2] = -Zr[hh][2]; c0[3] = -Zr[hh][3];
        c0 = mfma16(qf[hh][0], kf[n2][0], c0);
        c0 = mfma16(qf[hh][1], kf[n2][1], c0);
#pragma unroll
        for (int r = 0; r < 4; r++)
          Plds[((h0 + hh) * 16 + qd * 4 + r) * PSTR + n2 * 16 + ln] = (bf16_t)__expf(c0[r]);
      }
    }
    __syncthreads();
    // ---- head-mix, j-split: two passes of 4 k-elems (saves 16 VGPR vs
    // ma[4][8]; same FMA/cvt count; b64 instead of b128 P reads)
    bf16x8 af[4];
#pragma unroll
    for (int half = 0; half < 2; half++) {
      float mah[4][4];
#pragma unroll
      for (int g = 0; g < 4; g++)
#pragma unroll
        for (int j = 0; j < 4; j++) mah[g][j] = 0.f;
#pragma unroll
      for (int h = 0; h < H_; h++) {
        bf16x4 pf = *(const bf16x4*)&Plds[(h * 16 + ln) * PSTR + qd * 8 + half * 4];
        float pv[4];
#pragma unroll
        for (int j = 0; j < 4; j++) pv[j] = (float)pf[j];
#pragma unroll
        for (int g = 0; g < 4; g++) {
          float wgt = mixLds[(h0 + g) * 16 + h];
#pragma unroll
          for (int j = 0; j < 4; j++) mah[g][j] += wgt * pv[j];
        }
      }
#pragma unroll
      for (int g = 0; g < 4; g++)
#pragma unroll
        for (int j = 0; j < 4; j++) af[g][half * 4 + j] = (bf16_t)mah[g][j];
    }
    // ---- PV for groups h0..h0+3 over this k-tile
#pragma unroll
    for (int g = 0; g < 4; g++) {
#pragma unroll
      for (int nt = 0; nt < 4; nt++) {
        bf16x8 vf = *(const bf16x8*)&Vt[((size_t)((b * H_ + h0 + g) * 64 + nt * 16 + ln)) * S_ + kb + qd * 8];
        cacc[g][nt] = mfma16(af[g], vf, cacc[g][nt]);
      }
    }
    __syncthreads();
  }
  float* dst = pp + (size_t)kg * B_ * S_ * E_;
#pragma unroll
  for (int g = 0; g < 4; g++)
#pragma unroll
    for (int nt = 0; nt < 4; nt++)
#pragma unroll
      for (int r = 0; r < 4; r++)
        dst[(rowbase + q0 + qd * 4 + r) * E_ + (h0 + g) * 64 + nt * 16 + ln] = cacc[g][nt][r];
}

// ---------------------------------------------------------------------------
extern "C" void kernel_launch(void* const* d_in, const int* in_sizes, int n_in,
                              void* d_out, int out_size, void* d_ws, size_t ws_size,
                              hipStream_t stream) {
  const float* query = (const float*)d_in[0];
  const float* key_  = (const float*)d_in[1];
  const float* value = (const float*)d_in[2];
  const float* Wq = (const float*)d_in[3];
  const float* bq = (const float*)d_in[4];
  const float* Wk = (const float*)d_in[5];
  const float* bk = (const float*)d_in[6];
  const float* Wv = (const float*)d_in[7];
  const float* bv = (const float*)d_in[8];
  const float* hm = (const float*)d_in[9];
  const float* Wo = (const float*)d_in[10];
  const float* bo = (const float*)d_in[11];
  float* out = (float*)d_out;

  char* ws = (char*)d_ws;
  size_t off = 0;
  auto alloc = [&](size_t bytes) -> void* {
    void* p = ws + off;
    off += (bytes + 255) & ~(size_t)255;
    return p;
  };
  // ---- workspace ~67 MB ----
  float*  MIXW = (float*) alloc(256 * 4);
  float*  Zb   = (float*) alloc((size_t)B_ * H_ * S_ * 4);      // 256 KB
  bf16_t* Qp   = (bf16_t*)alloc((size_t)B_ * S_ * E_ * 2);      // 8.4 MB
  bf16_t* Kp   = (bf16_t*)alloc((size_t)B_ * S_ * E_ * 2);      // 8.4 MB
  bf16_t* Vp   = (bf16_t*)alloc((size_t)B_ * S_ * E_ * 2);      // 8.4 MB
  bf16_t* Vtt  = (bf16_t*)alloc((size_t)B_ * S_ * E_ * 2);      // 8.4 MB
  float*  PP   = (float*) alloc((size_t)2 * B_ * S_ * E_ * 4);  // 33.6 MB (2 k-halves)
  (void)in_sizes; (void)n_in; (void)out_size; (void)ws_size;

  mix_kernel<<<1, 256, 0, stream>>>(hm, MIXW);

  GemmSec sq{query, nullptr, bq, Wq, Qp, 0.125f};
  GemmSec sk{key_,  nullptr, bk, Wk, Kp, 1.f};
  GemmSec sv{value, nullptr, bv, Wv, Vp, 1.f};
  gemm_kernel<true, false, false><<<dim3(8, 32, 3), 256, 0, stream>>>(sq, sk, sv);

  transpose_v_kernel<<<dim3(64, 2, 32), 256, 0, stream>>>(Vp, Vtt);
  pass1_kernel<<<dim3(32, 32, 1), 256, 0, stream>>>(Qp, Kp, Zb);
  pass2_kernel<<<dim3(512, 1, 1), 256, 0, stream>>>(Qp, Kp, Vtt, Zb, MIXW, PP);

  float* PP1 = PP + (size_t)B_ * S_ * E_;
  GemmSec so{PP, PP1, bo, Wo, out, 1.f};
  gemm_kernel<true, true, true><<<dim3(8, 32, 1), 256, 0, stream>>>(so, so, so);
}

// Round 8
// 683.330 us; speedup vs baseline: 1.2297x; 1.2297x over previous
//
#include <hip/hip_runtime.h>
#include <hip/hip_bf16.h>
#include <cstdint>
#include <cstddef>

// ---------------------------------------------------------------------------
// EnhancedMultiHeadAttention on MI355X (gfx950).
// EXTERNAL dtype: fp32 (per reference). INTERNAL: bf16 MFMA, fp32 stats.
// Pipeline:
//   mix_kernel   : softmax(head_mixing fp32) -> MIXW fp32[16][16]
//   gemm<f32in>  : Q/K/V projections (A fp32->bf16, W fp32 transposed in LDS),
//                  Q pre-scaled 1/8.
//   transpose_v  : Vp[b,s,g*64+d] -> Vt[b,g,d,s]   (bf16)
//   pass1        : Z[b,h,q] = m + log l  (flash stats, MFMA QK^T), 1024 blocks.
//   pass2        : p=exp(s-Z), head-mix (VALU), PV (MFMA) -> f32 PARTIALS
//     R10 = R1-layout x R8-split-K. Allocator evidence: R1's 8-wave layout
//     (2 heads + 2 groups per wave) measured VGPR 64, ZERO scratch; every
//     attempt to host more state per thread (R0/R6 4+4: 196+64 regs -> 1
//     wave/SIMD; R7 waves_per_eu(2): compiler picked 128 and spilled
//     loop-invariants, +226 MB re-read traffic). So: keep R1's per-wave
//     register layout verbatim, remove its QK^T duplication via the R8
//     cross-block k-split, keep R7's conflict-free PSTR 36.
//     Grid 512 = (b, qt128, khalf) x 512 thr (8 waves) -> 2 blocks/CU
//     = 4 waves/SIMD, no spills, no duplicated work.
//   gemm<f32out> : (PP0+PP1) @ Wo + bo -> d_out fp32
// MFMA 16x16x32 bf16 layouts (m89/m91/m120-verified):
//   A: m=lane&15, k=(lane>>4)*8+j ; B: n=lane&15, k=(lane>>4)*8+j
//   C/D: col=lane&15, row=(lane>>4)*4+reg
// ---------------------------------------------------------------------------

typedef __bf16 bf16_t;
typedef __bf16 bf16x8 __attribute__((ext_vector_type(8)));
typedef float f32x4 __attribute__((ext_vector_type(4)));

#define B_ 2
#define S_ 2048
#define E_ 1024
#define H_ 16
#define D_ 64
#define PSTR 36  // padded k-stride of P tile in bf16 (72 B rows; R7: 0 conflicts)

static __device__ __forceinline__ f32x4 mfma16(bf16x8 a, bf16x8 b, f32x4 c) {
  return __builtin_amdgcn_mfma_f32_16x16x32_bf16(a, b, c, 0, 0, 0);
}

// ---------------- mix = softmax(head_mixing, axis=-1), fp32 ----------------
__global__ void mix_kernel(const float* __restrict__ hm, float* __restrict__ mixw) {
  int g = threadIdx.x;
  if (g < H_) {
    float v[H_]; float mx = -1e30f;
    for (int h = 0; h < H_; h++) { v[h] = hm[g * H_ + h]; mx = fmaxf(mx, v[h]); }
    float s = 0.f;
    for (int h = 0; h < H_; h++) { v[h] = __expf(v[h] - mx); s += v[h]; }
    float inv = 1.f / s;
    for (int h = 0; h < H_; h++) mixw[g * H_ + h] = v[h] * inv;
  }
}

// ---------------- V transpose: Vp[b,s,g*64+d] -> Vt[(b*16+g)*64+d][s] ------
__global__ void transpose_v_kernel(const bf16_t* __restrict__ Vp, bf16_t* __restrict__ Vt) {
  __shared__ bf16_t t[32][33];
  const int tx = threadIdx.x & 31, ty = threadIdx.x >> 5;
  const int z = blockIdx.z, b = z >> 4, g = z & 15;
  const int s0 = blockIdx.x * 32, d0 = blockIdx.y * 32;
  const bf16_t* src = Vp + (size_t)b * S_ * E_ + g * 64;
  bf16_t* dst = Vt + (size_t)z * 64 * S_;
#pragma unroll
  for (int i = 0; i < 4; i++)
    t[ty + i * 8][tx] = src[(size_t)(s0 + ty + i * 8) * E_ + d0 + tx];
  __syncthreads();
#pragma unroll
  for (int i = 0; i < 4; i++)
    dst[(size_t)(d0 + ty + i * 8) * S_ + s0 + tx] = t[tx][ty + i * 8];
}

// ---------------- GEMM: C[4096,1024] = (A @ W + bias) * scale --------------
// AF32: A fp32 (else bf16). ASUM: A = A + A2 elementwise (both fp32).
// OF32: C fp32 (else bf16).
struct GemmSec {
  const void* A; const void* A2; const float* bias; const float* W; void* C; float scale;
};

template <bool AF32, bool OF32, bool ASUM>
__global__ __launch_bounds__(256) void gemm_kernel(GemmSec s0, GemmSec s1, GemmSec s2) {
  const int z = blockIdx.z;
  GemmSec p = (z == 0) ? s0 : ((z == 1) ? s1 : s2);
  const int tid = threadIdx.x;
  const int wave = tid >> 6, lane = tid & 63;
  const int ln = lane & 15, qd = lane >> 4;
  const int wm = wave >> 1, wn = wave & 1;
  const int row0 = blockIdx.y * 128, col0 = blockIdx.x * 128;

  __shared__ __align__(16) bf16_t As[128 * 32];  // [row 128][k 32]
  __shared__ __align__(16) bf16_t Bs[128 * 32];  // [n 128][k 32]

  f32x4 z4 = {0.f, 0.f, 0.f, 0.f};
  f32x4 acc[4][4];
#pragma unroll
  for (int i = 0; i < 4; i++)
#pragma unroll
    for (int j = 0; j < 4; j++) acc[i][j] = z4;

  for (int ks = 0; ks < E_ / 32; ks++) {
    const int kk = ks * 32;
#pragma unroll
    for (int cc = 0; cc < 2; cc++) {
      const int c = tid + cc * 256;
      const int r = c >> 2, kc = (c & 3) * 8;
      if (AF32) {
        const float* Af = (const float*)p.A;
        f32x4 f0 = *(const f32x4*)&Af[(size_t)(row0 + r) * E_ + kk + kc];
        f32x4 f1 = *(const f32x4*)&Af[(size_t)(row0 + r) * E_ + kk + kc + 4];
        if (ASUM) {
          const float* Ag = (const float*)p.A2;
          f0 += *(const f32x4*)&Ag[(size_t)(row0 + r) * E_ + kk + kc];
          f1 += *(const f32x4*)&Ag[(size_t)(row0 + r) * E_ + kk + kc + 4];
        }
        bf16x8 v;
#pragma unroll
        for (int j = 0; j < 4; j++) { v[j] = (bf16_t)f0[j]; v[4 + j] = (bf16_t)f1[j]; }
        *(bf16x8*)&As[r * 32 + kc] = v;
      } else {
        const bf16_t* Ab = (const bf16_t*)p.A;
        *(uint4*)&As[r * 32 + kc] = *(const uint4*)&Ab[(size_t)(row0 + r) * E_ + kk + kc];
      }
    }
#pragma unroll
    for (int cc = 0; cc < 2; cc++) {
      const int c = tid + cc * 256;
      const int kr = c & 31, nc = (c >> 5) * 8;
      f32x4 g0 = *(const f32x4*)&p.W[(size_t)(kk + kr) * E_ + col0 + nc];
      f32x4 g1 = *(const f32x4*)&p.W[(size_t)(kk + kr) * E_ + col0 + nc + 4];
#pragma unroll
      for (int j = 0; j < 4; j++) {
        Bs[(nc + j) * 32 + kr]     = (bf16_t)g0[j];
        Bs[(nc + 4 + j) * 32 + kr] = (bf16_t)g1[j];
      }
    }
    __syncthreads();
    bf16x8 af[4], bfr[4];
#pragma unroll
    for (int mt = 0; mt < 4; mt++) af[mt] = *(const bf16x8*)&As[(wm * 64 + mt * 16 + ln) * 32 + qd * 8];
#pragma unroll
    for (int nt = 0; nt < 4; nt++) bfr[nt] = *(const bf16x8*)&Bs[(wn * 64 + nt * 16 + ln) * 32 + qd * 8];
#pragma unroll
    for (int mt = 0; mt < 4; mt++)
#pragma unroll
      for (int nt = 0; nt < 4; nt++)
        acc[mt][nt] = mfma16(af[mt], bfr[nt], acc[mt][nt]);
    __syncthreads();
  }
#pragma unroll
  for (int nt = 0; nt < 4; nt++) {
    int col = col0 + wn * 64 + nt * 16 + ln;
    float bias_v = p.bias[col];
#pragma unroll
    for (int mt = 0; mt < 4; mt++) {
      int row = row0 + wm * 64 + mt * 16 + qd * 4;
#pragma unroll
      for (int r = 0; r < 4; r++) {
        float v = (acc[mt][nt][r] + bias_v) * p.scale;
        if (OF32) ((float*)p.C)[(size_t)(row + r) * E_ + col] = v;
        else      ((bf16_t*)p.C)[(size_t)(row + r) * E_ + col] = (bf16_t)v;
      }
    }
  }
}

// ---------------- pass 1: softmax stats Z = m + log(l) ---------------------
// grid (32,32), each wave handles 16 q rows -> 1024 blocks = 4 blocks/CU.
__global__ __launch_bounds__(256, 4) void pass1_kernel(const bf16_t* __restrict__ Qp,
                                                       const bf16_t* __restrict__ Kp,
                                                       float* __restrict__ Z) {
  const int qc = blockIdx.x;            // 0..31
  const int bh = blockIdx.y;
  const int b = bh >> 4, h = bh & 15;
  const int tid = threadIdx.x;
  const int wave = tid >> 6, lane = tid & 63;
  const int ln = lane & 15, qd = lane >> 4;
  const size_t rowbase = (size_t)b * S_;
  const int qbase = qc * 64 + wave * 16;

  bf16x8 qf[2];
#pragma unroll
  for (int db = 0; db < 2; db++)
    qf[db] = *(const bf16x8*)&Qp[(rowbase + qbase + ln) * E_ + h * 64 + db * 32 + qd * 8];

  float m[4], l[4];
#pragma unroll
  for (int r = 0; r < 4; r++) { m[r] = -1e30f; l[r] = 0.f; }

  for (int kt = 0; kt < S_ / 64; kt++) {
    bf16x8 kf[4][2];
#pragma unroll
    for (int nt = 0; nt < 4; nt++)
#pragma unroll
      for (int db = 0; db < 2; db++)
        kf[nt][db] = *(const bf16x8*)&Kp[(rowbase + kt * 64 + nt * 16 + ln) * E_ + h * 64 + db * 32 + qd * 8];
    f32x4 sc[4];
#pragma unroll
    for (int nt = 0; nt < 4; nt++) {
      f32x4 c0 = {0.f, 0.f, 0.f, 0.f};
      c0 = mfma16(qf[0], kf[nt][0], c0);
      sc[nt] = mfma16(qf[1], kf[nt][1], c0);
    }
#pragma unroll
    for (int r = 0; r < 4; r++) {
      float tmax = fmaxf(fmaxf(sc[0][r], sc[1][r]), fmaxf(sc[2][r], sc[3][r]));
      float mn = fmaxf(m[r], tmax);
      float add = __expf(sc[0][r] - mn) + __expf(sc[1][r] - mn) +
                  __expf(sc[2][r] - mn) + __expf(sc[3][r] - mn);
      l[r] = l[r] * __expf(m[r] - mn) + add;
      m[r] = mn;
    }
  }
#pragma unroll
  for (int r = 0; r < 4; r++) {
    float mm = m[r], ll = l[r];
    for (int mask = 1; mask < 16; mask <<= 1) {
      float mo = __shfl_xor(mm, mask);
      float lo = __shfl_xor(ll, mask);
      float mn = fmaxf(mm, mo);
      ll = ll * __expf(mm - mn) + lo * __expf(mo - mn);
      mm = mn;
    }
    if (ln == 0) {
      int q = qbase + qd * 4 + r;
      Z[(size_t)bh * S_ + q] = mm + __logf(ll);
    }
  }
}

// ---------------- pass 2: p=exp(s-Z), head-mix, PV -> f32 partials ---------
// R10: cross-block split-K with R1's proven register layout.
// grid 512 = (b<<8)|(qt<<1)|kg, 512 thr / 8 waves.
// Wave wi: QK^T+exp for heads {2wi,2wi+1} over this block's k-half into the
// shared 16-head Plds (no duplication); head-mix (all 16 h) + PV for output
// groups {2wi,2wi+1}. f32 partials to pp[kg]; halves summed in Wo-GEMM
// A-staging. Per-thread: qf 16 + Zr 8 + kf 16 + ma 16 + cacc 32(acc) ~= 96
// regs -- the layout R1 measured at VGPR 64, zero scratch.
__global__ __launch_bounds__(512) void pass2_kernel(const bf16_t* __restrict__ Qp,
                                                    const bf16_t* __restrict__ Kp,
                                                    const bf16_t* __restrict__ Vt,
                                                    const float* __restrict__ Z,
                                                    const float* __restrict__ mixw,
                                                    float* __restrict__ pp) {
  const int id = blockIdx.x;            // 0..511
  const int kg = id & 1;                // k-half
  const int qt = (id >> 1) & 127;
  const int b  = id >> 8;
  const int q0 = qt * 16;

  const int tid = threadIdx.x;
  const int wave = tid >> 6, lane = tid & 63;
  const int ln = lane & 15, qd = lane >> 4;
  const int h0 = wave * 2;              // 2 source heads == 2 output groups

  __shared__ __align__(16) bf16_t Plds[16 * 16 * PSTR];  // [h][q16][k PSTR]
  __shared__ float mixLds[256];
  if (tid < 256) mixLds[tid] = mixw[tid];
  // first mixLds read is after the loop's first __syncthreads -> safe

  const size_t rowbase = (size_t)b * S_;
  const int kbase = kg * (S_ / 2);      // contiguous k-half

  bf16x8 qf[2][2];
#pragma unroll
  for (int hh = 0; hh < 2; hh++)
#pragma unroll
    for (int db = 0; db < 2; db++)
      qf[hh][db] = *(const bf16x8*)&Qp[(rowbase + q0 + ln) * E_ + (h0 + hh) * 64 + db * 32 + qd * 8];

  float Zr[2][4];
#pragma unroll
  for (int hh = 0; hh < 2; hh++)
#pragma unroll
    for (int r = 0; r < 4; r++)
      Zr[hh][r] = Z[((size_t)(b * H_ + h0 + hh)) * S_ + q0 + qd * 4 + r];

  f32x4 z4 = {0.f, 0.f, 0.f, 0.f};
  f32x4 cacc[2][4];
#pragma unroll
  for (int gg = 0; gg < 2; gg++)
#pragma unroll
    for (int nt = 0; nt < 4; nt++) cacc[gg][nt] = z4;

  for (int t = 0; t < S_ / 64; t++) {   // 32 iters over this k-half
    const int kb = kbase + t * 32;
    // ---- QK^T + exp for this wave's 2 heads into Plds
#pragma unroll
    for (int hh = 0; hh < 2; hh++) {
      bf16x8 kf[2][2];
#pragma unroll
      for (int n2 = 0; n2 < 2; n2++)
#pragma unroll
        for (int db = 0; db < 2; db++)
          kf[n2][db] = *(const bf16x8*)&Kp[(rowbase + kb + n2 * 16 + ln) * E_ + (h0 + hh) * 64 + db * 32 + qd * 8];
#pragma unroll
      for (int n2 = 0; n2 < 2; n2++) {
        f32x4 c0;
        c0[0] = -Zr[hh][0]; c0[1] = -Zr[hh][1]; c0[2] = -Zr[hh][2]; c0[3] = -Zr[hh][3];
        c0 = mfma16(qf[hh][0], kf[n2][0], c0);
        c0 = mfma16(qf[hh][1], kf[n2][1], c0);
#pragma unroll
        for (int r = 0; r < 4; r++)
          Plds[((h0 + hh) * 16 + qd * 4 + r) * PSTR + n2 * 16 + ln] = (bf16_t)__expf(c0[r]);
      }
    }
    __syncthreads();
    // ---- head-mix: all 16 heads, 2 output groups
    float ma[2][8];
#pragma unroll
    for (int gg = 0; gg < 2; gg++)
#pragma unroll
      for (int j = 0; j < 8; j++) ma[gg][j] = 0.f;
#pragma unroll
    for (int h = 0; h < H_; h++) {
      bf16x8 pf = *(const bf16x8*)&Plds[(h * 16 + ln) * PSTR + qd * 8];
      float w0 = mixLds[h0 * 16 + h];
      float w1 = mixLds[(h0 + 1) * 16 + h];
#pragma unroll
      for (int j = 0; j < 8; j++) {
        float pv = (float)pf[j];
        ma[0][j] += w0 * pv;
        ma[1][j] += w1 * pv;
      }
    }
    // ---- PV for groups h0, h0+1 over this k-tile
#pragma unroll
    for (int gg = 0; gg < 2; gg++) {
      bf16x8 af;
#pragma unroll
      for (int j = 0; j < 8; j++) af[j] = (bf16_t)ma[gg][j];
#pragma unroll
      for (int nt = 0; nt < 4; nt++) {
        bf16x8 vf = *(const bf16x8*)&Vt[((size_t)((b * H_ + h0 + gg) * 64 + nt * 16 + ln)) * S_ + kb + qd * 8];
        cacc[gg][nt] = mfma16(af, vf, cacc[gg][nt]);
      }
    }
    __syncthreads();
  }
  float* dst = pp + (size_t)kg * B_ * S_ * E_;
#pragma unroll
  for (int gg = 0; gg < 2; gg++)
#pragma unroll
    for (int nt = 0; nt < 4; nt++)
#pragma unroll
      for (int r = 0; r < 4; r++)
        dst[(rowbase + q0 + qd * 4 + r) * E_ + (h0 + gg) * 64 + nt * 16 + ln] = cacc[gg][nt][r];
}

// ---------------------------------------------------------------------------
extern "C" void kernel_launch(void* const* d_in, const int* in_sizes, int n_in,
                              void* d_out, int out_size, void* d_ws, size_t ws_size,
                              hipStream_t stream) {
  const float* query = (const float*)d_in[0];
  const float* key_  = (const float*)d_in[1];
  const float* value = (const float*)d_in[2];
  const float* Wq = (const float*)d_in[3];
  const float* bq = (const float*)d_in[4];
  const float* Wk = (const float*)d_in[5];
  const float* bk = (const float*)d_in[6];
  const float* Wv = (const float*)d_in[7];
  const float* bv = (const float*)d_in[8];
  const float* hm = (const float*)d_in[9];
  const float* Wo = (const float*)d_in[10];
  const float* bo = (const float*)d_in[11];
  float* out = (float*)d_out;

  char* ws = (char*)d_ws;
  size_t off = 0;
  auto alloc = [&](size_t bytes) -> void* {
    void* p = ws + off;
    off += (bytes + 255) & ~(size_t)255;
    return p;
  };
  // ---- workspace ~67 MB ----
  float*  MIXW = (float*) alloc(256 * 4);
  float*  Zb   = (float*) alloc((size_t)B_ * H_ * S_ * 4);      // 256 KB
  bf16_t* Qp   = (bf16_t*)alloc((size_t)B_ * S_ * E_ * 2);      // 8.4 MB
  bf16_t* Kp   = (bf16_t*)alloc((size_t)B_ * S_ * E_ * 2);      // 8.4 MB
  bf16_t* Vp   = (bf16_t*)alloc((size_t)B_ * S_ * E_ * 2);      // 8.4 MB
  bf16_t* Vtt  = (bf16_t*)alloc((size_t)B_ * S_ * E_ * 2);      // 8.4 MB
  float*  PP   = (float*) alloc((size_t)2 * B_ * S_ * E_ * 4);  // 33.6 MB (2 k-halves)
  (void)in_sizes; (void)n_in; (void)out_size; (void)ws_size;

  mix_kernel<<<1, 256, 0, stream>>>(hm, MIXW);

  GemmSec sq{query, nullptr, bq, Wq, Qp, 0.125f};
  GemmSec sk{key_,  nullptr, bk, Wk, Kp, 1.f};
  GemmSec sv{value, nullptr, bv, Wv, Vp, 1.f};
  gemm_kernel<true, false, false><<<dim3(8, 32, 3), 256, 0, stream>>>(sq, sk, sv);

  transpose_v_kernel<<<dim3(64, 2, 32), 256, 0, stream>>>(Vp, Vtt);
  pass1_kernel<<<dim3(32, 32, 1), 256, 0, stream>>>(Qp, Kp, Zb);
  pass2_kernel<<<dim3(512, 1, 1), 512, 0, stream>>>(Qp, Kp, Vtt, Zb, MIXW, PP);

  float* PP1 = PP + (size_t)B_ * S_ * E_;
  GemmSec so{PP, PP1, bo, Wo, out, 1.f};
  gemm_kernel<true, true, true><<<dim3(8, 32, 1), 256, 0, stream>>>(so, so, so);
}

// Round 9
// 620.082 us; speedup vs baseline: 1.3551x; 1.1020x over previous
//
#include <hip/hip_runtime.h>
#include <hip/hip_bf16.h>
#include <cstdint>
#include <cstddef>

// ---------------------------------------------------------------------------
// EnhancedMultiHeadAttention on MI355X (gfx950).
// EXTERNAL dtype: fp32 (per reference). INTERNAL: bf16 MFMA, fp32 stats.
// Pipeline:
//   mix_kernel   : softmax(head_mixing fp32) -> MIXW fp32[16][16]
//   gemm<f32in>  : Q/K/V projections (A fp32->bf16, W fp32 transposed in LDS),
//                  Q pre-scaled 1/8.
//   transpose_v  : Vp[b,s,g*64+d] -> Vt[b,g,d,s]   (bf16)
//   pass1        : Z[b,h,q] = m + log l  (flash stats, MFMA QK^T), 1024 blocks.
//   pass2        : p=exp(s-Z), MFMA head-mix, PV (MFMA) -> f32 PARTIALS
//     R11: head-mix moved to the matrix core. R8 counters: pass2 329 us,
//     MfmaUtil 4.2 / VALU 24.7 / stall ~70%; the VALU mix was 384 insts/wave/
//     iter (serial LDS->FMA chain), and 120+32 regs blocked a 2nd block/CU.
//     mixed[g,q,k] = MIX[g,h] @ P[h,q,k] as 16x16x(16pad32) MFMA:
//       A = MIXW bf16 frag (4 VGPR, qd>=2 lanes zero = K-padding)
//       B = Pt[q][k][h] h-contiguous (HSTR 18) -> one b128 read per frag
//       D -> Mx[g][q][k] (GSTR 580) -> PV A-frags read unchanged.
//     4 mix-MFMAs/wave/iter replace 384 VALU insts; ma/mixLds regs freed
//     (state ~60 persistent) -> expect <=96 arch + 32 acc -> 2 blocks/CU.
//     All LDS strides bank-checked ~2-way (HSTR=18: 9-bank lane step;
//     GSTR=580: 8-bank qd step; Pt store 9-bank lane step).
//   gemm<f32out> : (PP0+PP1) @ Wo + bo -> d_out fp32
// MFMA 16x16x32 bf16 layouts (m89/m91/m120-verified):
//   A: m=lane&15, k=(lane>>4)*8+j ; B: n=lane&15, k=(lane>>4)*8+j
//   C/D: col=lane&15, row=(lane>>4)*4+reg ; D[m][n] = sum_k A[m,k]B[n,k]
// ---------------------------------------------------------------------------

typedef __bf16 bf16_t;
typedef __bf16 bf16x8 __attribute__((ext_vector_type(8)));
typedef float f32x4 __attribute__((ext_vector_type(4)));

#define B_ 2
#define S_ 2048
#define E_ 1024
#define H_ 16
#define D_ 64
#define HSTR 18   // Pt h-stride (16 h + 2 pad): lane k-step = 18 bf16 = 9 banks
#define GSTR 580  // Mx g-plane stride (16*36 + 4): qd g-step = 8 banks

static __device__ __forceinline__ f32x4 mfma16(bf16x8 a, bf16x8 b, f32x4 c) {
  return __builtin_amdgcn_mfma_f32_16x16x32_bf16(a, b, c, 0, 0, 0);
}

// ---------------- mix = softmax(head_mixing, axis=-1), fp32 ----------------
__global__ void mix_kernel(const float* __restrict__ hm, float* __restrict__ mixw) {
  int g = threadIdx.x;
  if (g < H_) {
    float v[H_]; float mx = -1e30f;
    for (int h = 0; h < H_; h++) { v[h] = hm[g * H_ + h]; mx = fmaxf(mx, v[h]); }
    float s = 0.f;
    for (int h = 0; h < H_; h++) { v[h] = __expf(v[h] - mx); s += v[h]; }
    float inv = 1.f / s;
    for (int h = 0; h < H_; h++) mixw[g * H_ + h] = v[h] * inv;
  }
}

// ---------------- V transpose: Vp[b,s,g*64+d] -> Vt[(b*16+g)*64+d][s] ------
__global__ void transpose_v_kernel(const bf16_t* __restrict__ Vp, bf16_t* __restrict__ Vt) {
  __shared__ bf16_t t[32][33];
  const int tx = threadIdx.x & 31, ty = threadIdx.x >> 5;
  const int z = blockIdx.z, b = z >> 4, g = z & 15;
  const int s0 = blockIdx.x * 32, d0 = blockIdx.y * 32;
  const bf16_t* src = Vp + (size_t)b * S_ * E_ + g * 64;
  bf16_t* dst = Vt + (size_t)z * 64 * S_;
#pragma unroll
  for (int i = 0; i < 4; i++)
    t[ty + i * 8][tx] = src[(size_t)(s0 + ty + i * 8) * E_ + d0 + tx];
  __syncthreads();
#pragma unroll
  for (int i = 0; i < 4; i++)
    dst[(size_t)(d0 + ty + i * 8) * S_ + s0 + tx] = t[tx][ty + i * 8];
}

// ---------------- GEMM: C[4096,1024] = (A @ W + bias) * scale --------------
// AF32: A fp32 (else bf16). ASUM: A = A + A2 elementwise (both fp32).
// OF32: C fp32 (else bf16).
struct GemmSec {
  const void* A; const void* A2; const float* bias; const float* W; void* C; float scale;
};

template <bool AF32, bool OF32, bool ASUM>
__global__ __launch_bounds__(256) void gemm_kernel(GemmSec s0, GemmSec s1, GemmSec s2) {
  const int z = blockIdx.z;
  GemmSec p = (z == 0) ? s0 : ((z == 1) ? s1 : s2);
  const int tid = threadIdx.x;
  const int wave = tid >> 6, lane = tid & 63;
  const int ln = lane & 15, qd = lane >> 4;
  const int wm = wave >> 1, wn = wave & 1;
  const int row0 = blockIdx.y * 128, col0 = blockIdx.x * 128;

  __shared__ __align__(16) bf16_t As[128 * 32];  // [row 128][k 32]
  __shared__ __align__(16) bf16_t Bs[128 * 32];  // [n 128][k 32]

  f32x4 z4 = {0.f, 0.f, 0.f, 0.f};
  f32x4 acc[4][4];
#pragma unroll
  for (int i = 0; i < 4; i++)
#pragma unroll
    for (int j = 0; j < 4; j++) acc[i][j] = z4;

  for (int ks = 0; ks < E_ / 32; ks++) {
    const int kk = ks * 32;
#pragma unroll
    for (int cc = 0; cc < 2; cc++) {
      const int c = tid + cc * 256;
      const int r = c >> 2, kc = (c & 3) * 8;
      if (AF32) {
        const float* Af = (const float*)p.A;
        f32x4 f0 = *(const f32x4*)&Af[(size_t)(row0 + r) * E_ + kk + kc];
        f32x4 f1 = *(const f32x4*)&Af[(size_t)(row0 + r) * E_ + kk + kc + 4];
        if (ASUM) {
          const float* Ag = (const float*)p.A2;
          f0 += *(const f32x4*)&Ag[(size_t)(row0 + r) * E_ + kk + kc];
          f1 += *(const f32x4*)&Ag[(size_t)(row0 + r) * E_ + kk + kc + 4];
        }
        bf16x8 v;
#pragma unroll
        for (int j = 0; j < 4; j++) { v[j] = (bf16_t)f0[j]; v[4 + j] = (bf16_t)f1[j]; }
        *(bf16x8*)&As[r * 32 + kc] = v;
      } else {
        const bf16_t* Ab = (const bf16_t*)p.A;
        *(uint4*)&As[r * 32 + kc] = *(const uint4*)&Ab[(size_t)(row0 + r) * E_ + kk + kc];
      }
    }
#pragma unroll
    for (int cc = 0; cc < 2; cc++) {
      const int c = tid + cc * 256;
      const int kr = c & 31, nc = (c >> 5) * 8;
      f32x4 g0 = *(const f32x4*)&p.W[(size_t)(kk + kr) * E_ + col0 + nc];
      f32x4 g1 = *(const f32x4*)&p.W[(size_t)(kk + kr) * E_ + col0 + nc + 4];
#pragma unroll
      for (int j = 0; j < 4; j++) {
        Bs[(nc + j) * 32 + kr]     = (bf16_t)g0[j];
        Bs[(nc + 4 + j) * 32 + kr] = (bf16_t)g1[j];
      }
    }
    __syncthreads();
    bf16x8 af[4], bfr[4];
#pragma unroll
    for (int mt = 0; mt < 4; mt++) af[mt] = *(const bf16x8*)&As[(wm * 64 + mt * 16 + ln) * 32 + qd * 8];
#pragma unroll
    for (int nt = 0; nt < 4; nt++) bfr[nt] = *(const bf16x8*)&Bs[(wn * 64 + nt * 16 + ln) * 32 + qd * 8];
#pragma unroll
    for (int mt = 0; mt < 4; mt++)
#pragma unroll
      for (int nt = 0; nt < 4; nt++)
        acc[mt][nt] = mfma16(af[mt], bfr[nt], acc[mt][nt]);
    __syncthreads();
  }
#pragma unroll
  for (int nt = 0; nt < 4; nt++) {
    int col = col0 + wn * 64 + nt * 16 + ln;
    float bias_v = p.bias[col];
#pragma unroll
    for (int mt = 0; mt < 4; mt++) {
      int row = row0 + wm * 64 + mt * 16 + qd * 4;
#pragma unroll
      for (int r = 0; r < 4; r++) {
        float v = (acc[mt][nt][r] + bias_v) * p.scale;
        if (OF32) ((float*)p.C)[(size_t)(row + r) * E_ + col] = v;
        else      ((bf16_t*)p.C)[(size_t)(row + r) * E_ + col] = (bf16_t)v;
      }
    }
  }
}

// ---------------- pass 1: softmax stats Z = m + log(l) ---------------------
// grid (32,32), each wave handles 16 q rows -> 1024 blocks = 4 blocks/CU.
__global__ __launch_bounds__(256, 4) void pass1_kernel(const bf16_t* __restrict__ Qp,
                                                       const bf16_t* __restrict__ Kp,
                                                       float* __restrict__ Z) {
  const int qc = blockIdx.x;            // 0..31
  const int bh = blockIdx.y;
  const int b = bh >> 4, h = bh & 15;
  const int tid = threadIdx.x;
  const int wave = tid >> 6, lane = tid & 63;
  const int ln = lane & 15, qd = lane >> 4;
  const size_t rowbase = (size_t)b * S_;
  const int qbase = qc * 64 + wave * 16;

  bf16x8 qf[2];
#pragma unroll
  for (int db = 0; db < 2; db++)
    qf[db] = *(const bf16x8*)&Qp[(rowbase + qbase + ln) * E_ + h * 64 + db * 32 + qd * 8];

  float m[4], l[4];
#pragma unroll
  for (int r = 0; r < 4; r++) { m[r] = -1e30f; l[r] = 0.f; }

  for (int kt = 0; kt < S_ / 64; kt++) {
    bf16x8 kf[4][2];
#pragma unroll
    for (int nt = 0; nt < 4; nt++)
#pragma unroll
      for (int db = 0; db < 2; db++)
        kf[nt][db] = *(const bf16x8*)&Kp[(rowbase + kt * 64 + nt * 16 + ln) * E_ + h * 64 + db * 32 + qd * 8];
    f32x4 sc[4];
#pragma unroll
    for (int nt = 0; nt < 4; nt++) {
      f32x4 c0 = {0.f, 0.f, 0.f, 0.f};
      c0 = mfma16(qf[0], kf[nt][0], c0);
      sc[nt] = mfma16(qf[1], kf[nt][1], c0);
    }
#pragma unroll
    for (int r = 0; r < 4; r++) {
      float tmax = fmaxf(fmaxf(sc[0][r], sc[1][r]), fmaxf(sc[2][r], sc[3][r]));
      float mn = fmaxf(m[r], tmax);
      float add = __expf(sc[0][r] - mn) + __expf(sc[1][r] - mn) +
                  __expf(sc[2][r] - mn) + __expf(sc[3][r] - mn);
      l[r] = l[r] * __expf(m[r] - mn) + add;
      m[r] = mn;
    }
  }
#pragma unroll
  for (int r = 0; r < 4; r++) {
    float mm = m[r], ll = l[r];
    for (int mask = 1; mask < 16; mask <<= 1) {
      float mo = __shfl_xor(mm, mask);
      float lo = __shfl_xor(ll, mask);
      float mn = fmaxf(mm, mo);
      ll = ll * __expf(mm - mn) + lo * __expf(mo - mn);
      mm = mn;
    }
    if (ln == 0) {
      int q = qbase + qd * 4 + r;
      Z[(size_t)bh * S_ + q] = mm + __logf(ll);
    }
  }
}

// ---------------- pass 2: p=exp(s-Z), MFMA mix, PV -> f32 partials ---------
// Cross-block split-K. grid 512 = (b<<8)|(qt<<1)|kg, 512 thr / 8 waves.
// Per iteration (k-tile 32):
//  A: wave computes QK^T+exp for heads {2w,2w+1} -> Pt[q][k][h] (h-contig)
//  B: mix via MFMA: D[g][col16] = MIXW(A-frag, h-pad-32) x Pt-cols(B-frag,
//     one b128 read) ; 4 MFMA/wave covering all (g, 512 qk cols) -> Mx[g][q][k]
//  C: PV: af = b128 from Mx for groups {2w,2w+1}; 8 MFMA into cacc.
// f32 partials to pp[kg]; halves summed in Wo-GEMM A-staging.
__global__ __launch_bounds__(512) void pass2_kernel(const bf16_t* __restrict__ Qp,
                                                    const bf16_t* __restrict__ Kp,
                                                    const bf16_t* __restrict__ Vt,
                                                    const float* __restrict__ Z,
                                                    const float* __restrict__ mixw,
                                                    float* __restrict__ pp) {
  const int id = blockIdx.x;            // 0..511
  const int kg = id & 1;                // k-half
  const int qt = (id >> 1) & 127;
  const int b  = id >> 8;
  const int q0 = qt * 16;

  const int tid = threadIdx.x;
  const int wave = tid >> 6, lane = tid & 63;
  const int ln = lane & 15, qd = lane >> 4;
  const int h0 = wave * 2;              // 2 source heads == 2 output groups

  __shared__ __align__(16) bf16_t Pt[16 * 32 * HSTR];  // [q][k][h] 18432 B
  __shared__ __align__(16) bf16_t Mx[16 * GSTR];       // [g][q*36+k] 18560 B

  const size_t rowbase = (size_t)b * S_;
  const int kbase = kg * (S_ / 2);      // contiguous k-half

  // MIXW A-fragment: A[m=g=ln][k=h=qd*8+j]; lanes qd>=2 carry the K-padding.
  bf16x8 mixA;
#pragma unroll
  for (int j = 0; j < 8; j++) mixA[j] = (bf16_t)0.f;
  if (qd < 2) {
#pragma unroll
    for (int j = 0; j < 8; j++) mixA[j] = (bf16_t)mixw[ln * 16 + qd * 8 + j];
  }

  bf16x8 qf[2][2];
#pragma unroll
  for (int hh = 0; hh < 2; hh++)
#pragma unroll
    for (int db = 0; db < 2; db++)
      qf[hh][db] = *(const bf16x8*)&Qp[(rowbase + q0 + ln) * E_ + (h0 + hh) * 64 + db * 32 + qd * 8];

  float Zr[2][4];
#pragma unroll
  for (int hh = 0; hh < 2; hh++)
#pragma unroll
    for (int r = 0; r < 4; r++)
      Zr[hh][r] = Z[((size_t)(b * H_ + h0 + hh)) * S_ + q0 + qd * 4 + r];

  f32x4 z4 = {0.f, 0.f, 0.f, 0.f};
  f32x4 cacc[2][4];
#pragma unroll
  for (int gg = 0; gg < 2; gg++)
#pragma unroll
    for (int nt = 0; nt < 4; nt++) cacc[gg][nt] = z4;

  for (int t = 0; t < S_ / 64; t++) {   // 32 iters over this k-half
    const int kb = kbase + t * 32;
    // ---- phase A: QK^T + exp for this wave's 2 heads -> Pt[q][k][h]
#pragma unroll
    for (int hh = 0; hh < 2; hh++) {
      bf16x8 kf[2][2];
#pragma unroll
      for (int n2 = 0; n2 < 2; n2++)
#pragma unroll
        for (int db = 0; db < 2; db++)
          kf[n2][db] = *(const bf16x8*)&Kp[(rowbase + kb + n2 * 16 + ln) * E_ + (h0 + hh) * 64 + db * 32 + qd * 8];
#pragma unroll
      for (int n2 = 0; n2 < 2; n2++) {
        f32x4 c0;
        c0[0] = -Zr[hh][0]; c0[1] = -Zr[hh][1]; c0[2] = -Zr[hh][2]; c0[3] = -Zr[hh][3];
        c0 = mfma16(qf[hh][0], kf[n2][0], c0);
        c0 = mfma16(qf[hh][1], kf[n2][1], c0);
#pragma unroll
        for (int r = 0; r < 4; r++)
          Pt[((qd * 4 + r) * 32 + n2 * 16 + ln) * HSTR + h0 + hh] = (bf16_t)__expf(c0[r]);
      }
    }
    __syncthreads();
    // ---- phase B: mix via MFMA. Wave owns col-chunks cc = wave*4 .. +3
    //      (col = cc*16+ln -> q = cc>>1, k = (cc&1)*16+ln).
    f32x4 mm[4];
#pragma unroll
    for (int i = 0; i < 4; i++) {
      const int cc = wave * 4 + i;
      const int q  = cc >> 1;
      const int k  = (cc & 1) * 16 + ln;
      bf16x8 pb;
      if (qd < 2) {
        pb = *(const bf16x8*)&Pt[(q * 32 + k) * HSTR + qd * 8];
      } else {
#pragma unroll
        for (int j = 0; j < 8; j++) pb[j] = (bf16_t)0.f;  // K-padding
      }
      mm[i] = mfma16(mixA, pb, z4);
    }
#pragma unroll
    for (int i = 0; i < 4; i++) {
      const int cc = wave * 4 + i;
      const int q  = cc >> 1;
      const int k  = (cc & 1) * 16 + ln;
#pragma unroll
      for (int r = 0; r < 4; r++)
        Mx[(qd * 4 + r) * GSTR + q * 36 + k] = (bf16_t)mm[i][r];
    }
    __syncthreads();
    // ---- phase C: PV for groups h0, h0+1 over this k-tile
#pragma unroll
    for (int gg = 0; gg < 2; gg++) {
      bf16x8 af = *(const bf16x8*)&Mx[(h0 + gg) * GSTR + ln * 36 + qd * 8];
#pragma unroll
      for (int nt = 0; nt < 4; nt++) {
        bf16x8 vf = *(const bf16x8*)&Vt[((size_t)((b * H_ + h0 + gg) * 64 + nt * 16 + ln)) * S_ + kb + qd * 8];
        cacc[gg][nt] = mfma16(af, vf, cacc[gg][nt]);
      }
    }
    __syncthreads();                     // Mx reads done before next phase B
  }
  float* dst = pp + (size_t)kg * B_ * S_ * E_;
#pragma unroll
  for (int gg = 0; gg < 2; gg++)
#pragma unroll
    for (int nt = 0; nt < 4; nt++)
#pragma unroll
      for (int r = 0; r < 4; r++)
        dst[(rowbase + q0 + qd * 4 + r) * E_ + (h0 + gg) * 64 + nt * 16 + ln] = cacc[gg][nt][r];
}

// ---------------------------------------------------------------------------
extern "C" void kernel_launch(void* const* d_in, const int* in_sizes, int n_in,
                              void* d_out, int out_size, void* d_ws, size_t ws_size,
                              hipStream_t stream) {
  const float* query = (const float*)d_in[0];
  const float* key_  = (const float*)d_in[1];
  const float* value = (const float*)d_in[2];
  const float* Wq = (const float*)d_in[3];
  const float* bq = (const float*)d_in[4];
  const float* Wk = (const float*)d_in[5];
  const float* bk = (const float*)d_in[6];
  const float* Wv = (const float*)d_in[7];
  const float* bv = (const float*)d_in[8];
  const float* hm = (const float*)d_in[9];
  const float* Wo = (const float*)d_in[10];
  const float* bo = (const float*)d_in[11];
  float* out = (float*)d_out;

  char* ws = (char*)d_ws;
  size_t off = 0;
  auto alloc = [&](size_t bytes) -> void* {
    void* p = ws + off;
    off += (bytes + 255) & ~(size_t)255;
    return p;
  };
  // ---- workspace ~67 MB ----
  float*  MIXW = (float*) alloc(256 * 4);
  float*  Zb   = (float*) alloc((size_t)B_ * H_ * S_ * 4);      // 256 KB
  bf16_t* Qp   = (bf16_t*)alloc((size_t)B_ * S_ * E_ * 2);      // 8.4 MB
  bf16_t* Kp   = (bf16_t*)alloc((size_t)B_ * S_ * E_ * 2);      // 8.4 MB
  bf16_t* Vp   = (bf16_t*)alloc((size_t)B_ * S_ * E_ * 2);      // 8.4 MB
  bf16_t* Vtt  = (bf16_t*)alloc((size_t)B_ * S_ * E_ * 2);      // 8.4 MB
  float*  PP   = (float*) alloc((size_t)2 * B_ * S_ * E_ * 4);  // 33.6 MB (2 k-halves)
  (void)in_sizes; (void)n_in; (void)out_size; (void)ws_size;

  mix_kernel<<<1, 256, 0, stream>>>(hm, MIXW);

  GemmSec sq{query, nullptr, bq, Wq, Qp, 0.125f};
  GemmSec sk{key_,  nullptr, bk, Wk, Kp, 1.f};
  GemmSec sv{value, nullptr, bv, Wv, Vp, 1.f};
  gemm_kernel<true, false, false><<<dim3(8, 32, 3), 256, 0, stream>>>(sq, sk, sv);

  transpose_v_kernel<<<dim3(64, 2, 32), 256, 0, stream>>>(Vp, Vtt);
  pass1_kernel<<<dim3(32, 32, 1), 256, 0, stream>>>(Qp, Kp, Zb);
  pass2_kernel<<<dim3(512, 1, 1), 512, 0, stream>>>(Qp, Kp, Vtt, Zb, MIXW, PP);

  float* PP1 = PP + (size_t)B_ * S_ * E_;
  GemmSec so{PP, PP1, bo, Wo, out, 1.f};
  gemm_kernel<true, true, true><<<dim3(8, 32, 1), 256, 0, stream>>>(so, so, so);
}